// Round 14
// baseline (233.166 us; speedup 1.0000x reference)
//
#include <hip/hip_runtime.h>

typedef float  f32x2 __attribute__((ext_vector_type(2)));
typedef float  f32x4 __attribute__((ext_vector_type(4)));
typedef __fp16 f16x2 __attribute__((ext_vector_type(2)));

#define T_LEN 2048
#define GROUP 16
#define NG    (T_LEN / GROUP)      /* 128 groups */
#define NT    (NG + 3)             /* 131 ticks */
#define KH    28.853901f           /* 20*log2(e) */

/* 1/(1+exp2(z)) */
__device__ __forceinline__ float hs_neg(float z) {
    float e = __builtin_amdgcn_exp2f(z);
    return __builtin_amdgcn_rcpf(1.0f + e);
}

#define WAITV(N) asm volatile("s_waitcnt vmcnt(" #N ")" ::: "memory")
#define WAITL()  asm volatile("s_waitcnt lgkmcnt(0)" ::: "memory")
/* raw barrier (NOT __syncthreads: that drains vmcnt(0), killing DMA prefetch) */
#define TICK_BARRIER() do {                                   \
    asm volatile("s_waitcnt lgkmcnt(0)" ::: "memory");        \
    __builtin_amdgcn_s_barrier();                             \
    __builtin_amdgcn_sched_barrier(0); } while (0)

/* one 16-step group = 12 f32x4 per lane; wave-uniform LDS base + lane*16 */
#define DMA_GROUP(SET, SLOT, ROW, G) do {                                      \
    const float* g_ = (ROW) + (size_t)(G) * 48;                                \
    _Pragma("unroll")                                                          \
    for (int j_ = 0; j_ < 12; ++j_) {                                          \
        __builtin_amdgcn_global_load_lds(                                      \
            (const __attribute__((address_space(1))) void*)(g_ + 4 * j_),      \
            (__attribute__((address_space(3))) void*)&s_in[SET][SLOT][j_][0],  \
            16, 0, 0);                                                         \
    } } while (0)

__global__ __launch_bounds__(256, 1)
void xaj_ilp2_kernel(const float* __restrict__ inp,
                     const float* __restrict__ p_wum,
                     const float* __restrict__ p_wlm,
                     const float* __restrict__ p_wdm,
                     const float* __restrict__ p_c,
                     const float* __restrict__ p_b,
                     const float* __restrict__ p_k1,
                     const float* __restrict__ p_k2,
                     const float* __restrict__ p_k3,
                     float* __restrict__ out)
{
    /* 4-wave lockstep pipeline (W0 wu | W1 wl | W2 wd | W3 out), each lane
       carrying TWO independent chains (A,B) register-interleaved -> ILP=2 on
       the serial sigmoid chain. Rings identical to r11, duplicated per set:
       s_in ring-2, kremd1 ring-2, kud2 ring-2, kwd ring-2 (f16), wup ring-4. */
    __shared__ f32x4        s_in    [2][2][12][64];      /* 49152 B */
    __shared__ f32x2        s_kremd1[2][2][GROUP][64];   /* 32768 B */
    __shared__ f32x2        s_kud2  [2][2][GROUP][64];   /* 32768 B */
    __shared__ __fp16       s_kwd   [2][2][GROUP][64];   /*  8192 B */
    __shared__ unsigned int s_wup   [2][4][GROUP][64];   /* 32768 B */

    const int lane  = threadIdx.x & 63;
    const int wv    = threadIdx.x >> 6;        /* 0..3 */
    const int cA    = blockIdx.x * 128 + lane;
    const int cB    = cA + 64;
    const float* __restrict__ rowA = inp + (size_t)cA * (3 * T_LEN);
    const float* __restrict__ rowB = inp + (size_t)cB * (3 * T_LEN);
    float* __restrict__ orowA      = out + (size_t)cA * T_LEN;
    float* __restrict__ orowB      = out + (size_t)cB * T_LEN;

    const float wum = p_wum[0], wlm = p_wlm[0], wdm = p_wdm[0];
    const float cc  = p_c[0],   bb  = p_b[0];
    const float k1  = p_k1[0],  k2  = p_k2[0],  k3 = p_k3[0];

    /* runoff_production called as (wu, wd, wl, p, wum, wdm, wlm, b, c) */
    const float w_total = (wum * 19.9f + 0.1f)
                        + (wdm * 30.0f + 60.0f)
                        + (wlm * 60.0f + 60.0f);
    const float inv_wt = 1.0f / w_total;
    const float c_s = cc * 0.19f + 0.01f;
    const float b_s = bb * 0.3f  + 0.1f;
    const float k1s = k1 * 0.69f + 0.01f;
    const float k2s = k2 * 0.69f + 0.01f;
    const float k3s = k3 * 0.89f + 0.01f;
    const float Kq = k1s + 0.5f * k2s * (1.0f - k1s)
                   + 0.25f * k3s * (1.0f - k1s) * (1.0f - k2s);
    const float C1    = inv_wt / KH;
    const float invKH = 1.0f / KH;

    float KstA = 0.0f, KstB = 0.0f;            /* per-wave scan states */

    if (wv == 0) { DMA_GROUP(0, 0, rowA, 0); DMA_GROUP(1, 0, rowB, 0); }

#pragma clang loop unroll(disable)
    for (int T = 0; T < NT; ++T) {
        if (wv == 0) {
            /* ---- W0: wu-chain x2. Kwu' = Kp - arg*a, arg = KHpet - Kwu ---- */
            if (T < NG) {
                const int g = T;
                WAITV(0);                      /* group g DMA (issued T-1) */
                __builtin_amdgcn_sched_barrier(0);
                f32x4 fa[12], fb[12];
#pragma unroll
                for (int j = 0; j < 12; ++j) fa[j] = s_in[0][g & 1][j][lane];
#pragma unroll
                for (int j = 0; j < 12; ++j) fb[j] = s_in[1][g & 1][j][lane];
                WAITL();                       /* reads done before slot reuse */
                __builtin_amdgcn_sched_barrier(0);
                if (g + 1 < NG) {
                    DMA_GROUP(0, (g + 1) & 1, rowA, g + 1);
                    DMA_GROUP(1, (g + 1) & 1, rowB, g + 1);
                }
                float KwuA = KstA, KwuB = KstB;
#pragma unroll
                for (int j = 0; j < GROUP; ++j) {
                    const int k0 = 3 * j, k2i = 3 * j + 2;
                    float petA = fa[k0 >> 2][k0 & 3], pA = fa[k2i >> 2][k2i & 3];
                    float petB = fb[k0 >> 2][k0 & 3], pB = fb[k2i >> 2][k2i & 3];
                    float KpA = KH * pA, KpB = KH * pB;
                    float argA = fmaf(KH, petA, -KwuA);
                    float argB = fmaf(KH, petB, -KwuB);
                    float aA = hs_neg(argA), aB = hs_neg(argB);
                    float KwuAn = fmaf(-argA, aA, KpA);
                    float KwuBn = fmaf(-argB, aB, KpB);
                    float KyA = argA + (KwuAn - KpA);
                    float KyB = argB + (KwuBn - KpB);
                    float hxA = hs_neg(-KyA), hxB = hs_neg(-KyB);
                    f32x2 kdA = {hxA * KyA, KwuAn - KwuA};
                    f32x2 kdB = {hxB * KyB, KwuBn - KwuB};
                    s_kremd1[0][g & 1][j][lane] = kdA;
                    s_kremd1[1][g & 1][j][lane] = kdB;
                    f16x2 pkA = __builtin_amdgcn_cvt_pkrtz(KwuAn, KpA);
                    f16x2 pkB = __builtin_amdgcn_cvt_pkrtz(KwuBn, KpB);
                    s_wup[0][g & 3][j][lane] = __builtin_bit_cast(unsigned int, pkA);
                    s_wup[1][g & 3][j][lane] = __builtin_bit_cast(unsigned int, pkB);
                    KwuA = KwuAn; KwuB = KwuBn;
                }
                KstA = KwuA; KstB = KwuB;
            }
        } else if (wv == 1) {
            /* ---- W1: wl-chain x2. Kwl' = A - b2*harg ---- */
            if (T >= 1 && T <= NG) {
                const int g = T - 1;
                f32x2 kdA[GROUP], kdB[GROUP];
#pragma unroll
                for (int j = 0; j < GROUP; ++j) {
                    kdA[j] = s_kremd1[0][g & 1][j][lane];
                    kdB[j] = s_kremd1[1][g & 1][j][lane];
                }
                float KwlA = KstA, KwlB = KstB;
#pragma unroll
                for (int j = 0; j < GROUP; ++j) {
                    float KremA = kdA[j][0], Kd1A = kdA[j][1];
                    float KremB = kdB[j][0], Kd1B = kdB[j][1];
                    float hremA = hs_neg(-KremA), hremB = hs_neg(-KremB);
                    float SA = KwlA + Kd1A,     SB = KwlB + Kd1B;
                    float AA = fmaf(-hremA, KremA, SA);
                    float AB = fmaf(-hremB, KremB, SB);
                    float argA = KwlA - KremA,  argB = KwlB - KremB;
                    float b2A = hs_neg(argA),   b2B = hs_neg(argB);
                    float hargA = hremA * argA, hargB = hremB * argB;
                    float KwlAn = fmaf(-b2A, hargA, AA);
                    float KwlBn = fmaf(-b2B, hargB, AB);
                    float Ket2A = SA - KwlAn,   Ket2B = SB - KwlBn;
                    f32x2 udA = {KremA - Ket2A, Kd1A - Ket2A};
                    f32x2 udB = {KremB - Ket2B, Kd1B - Ket2B};
                    s_kud2[0][g & 1][j][lane] = udA;
                    s_kud2[1][g & 1][j][lane] = udB;
                    KwlA = KwlAn; KwlB = KwlBn;
                }
                KstA = KwlA; KstB = KwlB;
            }
        } else if (wv == 2) {
            /* ---- W2: wd-chain x2. Kwd' = A2 - c2*harg ---- */
            if (T >= 2 && T <= NG + 1) {
                const int g = T - 2;
                f32x2 udA[GROUP], udB[GROUP];
#pragma unroll
                for (int j = 0; j < GROUP; ++j) {
                    udA[j] = s_kud2[0][g & 1][j][lane];
                    udB[j] = s_kud2[1][g & 1][j][lane];
                }
                float KwdA = KstA, KwdB = KstB;
#pragma unroll
                for (int j = 0; j < GROUP; ++j) {
                    float KuA = udA[j][0], Kd2A = udA[j][1];
                    float KuB = udB[j][0], Kd2B = udB[j][1];
                    float huA = hs_neg(-KuA), huB = hs_neg(-KuB);
                    float S2A = KwdA + Kd2A,  S2B = KwdB + Kd2B;
                    float A2A = fmaf(-huA, KuA, S2A);
                    float A2B = fmaf(-huB, KuB, S2B);
                    float argA = KwdA - KuA,  argB = KwdB - KuB;
                    float c2A = hs_neg(argA), c2B = hs_neg(argB);
                    float hargA = huA * argA, hargB = huB * argB;
                    float KwdAn = fmaf(-c2A, hargA, A2A);
                    float KwdBn = fmaf(-c2B, hargB, A2B);
                    s_kwd[0][g & 1][j][lane] = (__fp16)KwdAn;
                    s_kwd[1][g & 1][j][lane] = (__fp16)KwdBn;
                    KwdA = KwdAn; KwdB = KwdBn;
                }
                KstA = KwdA; KstB = KwdB;
            }
        } else {
            /* ---- W3: stateless output x2 ---- */
            if (T >= 3) {
                const int g = T - 3;
                float qvA[GROUP], qvB[GROUP];
#pragma unroll
                for (int j = 0; j < GROUP; ++j) {
                    unsigned int pwA = s_wup[0][g & 3][j][lane];
                    unsigned int pwB = s_wup[1][g & 3][j][lane];
                    f16x2 pkA = __builtin_bit_cast(f16x2, pwA);
                    f16x2 pkB = __builtin_bit_cast(f16x2, pwB);
                    float KwuA_ = (float)pkA[0], pAv = (float)pkA[1] * invKH;
                    float KwuB_ = (float)pkB[0], pBv = (float)pkB[1] * invKH;
                    float KwdA_ = (float)s_kwd[0][g & 1][j][lane];
                    float KwdB_ = (float)s_kwd[1][g & 1][j][lane];
                    float ruA = KwuA_ * C1, rdA = KwdA_ * C1;
                    float ruB = KwuB_ * C1, rdB = KwdB_ * C1;
                    float s2A = fmaf(c_s * ruA, ruA, (b_s * rdA) * rdA);
                    float s2B = fmaf(c_s * ruB, ruB, (b_s * rdB) * rdB);
                    float psA = pAv - s2A, psB = pBv - s2B;
                    float soA = hs_neg(-KH * psA), soB = hs_neg(-KH * psB);
                    qvA[j] = psA * soA * Kq;
                    qvB[j] = psB * soB * Kq;
                }
                f32x4* oA = (f32x4*)(orowA + (size_t)g * GROUP);
                f32x4* oB = (f32x4*)(orowB + (size_t)g * GROUP);
#pragma unroll
                for (int i = 0; i < GROUP / 4; ++i) {
                    f32x4 qa = {qvA[4*i], qvA[4*i+1], qvA[4*i+2], qvA[4*i+3]};
                    f32x4 qb = {qvB[4*i], qvB[4*i+1], qvB[4*i+2], qvB[4*i+3]};
                    oA[i] = qa;
                    oB[i] = qb;
                }
            }
        }
        TICK_BARRIER();
    }
}

extern "C" void kernel_launch(void* const* d_in, const int* in_sizes, int n_in,
                              void* d_out, int out_size, void* d_ws, size_t ws_size,
                              hipStream_t stream) {
    const float* inp = (const float*)d_in[0];
    const int B = out_size / T_LEN;            // 4096
    dim3 block(256), grid(B / 128);            // 32 blocks, 2 chains/lane
    xaj_ilp2_kernel<<<grid, block, 0, stream>>>(
        inp,
        (const float*)d_in[1],  // wum
        (const float*)d_in[2],  // wlm
        (const float*)d_in[3],  // wdm
        (const float*)d_in[4],  // c
        (const float*)d_in[5],  // b
        (const float*)d_in[6],  // k1
        (const float*)d_in[7],  // k2
        (const float*)d_in[8],  // k3
        (float*)d_out);
}

// Round 16
// 160.946 us; speedup vs baseline: 1.4487x; 1.4487x over previous
//
#include <hip/hip_runtime.h>

typedef float  f32x4 __attribute__((ext_vector_type(4)));
typedef __fp16 f16x2 __attribute__((ext_vector_type(2)));

#define T_LEN 2048
#define GROUP 32
#define NG    (T_LEN / GROUP)      /* 64 groups */
#define NT    (NG + 3)             /* 67 ticks, 4-stage lockstep pipeline */
#define K2    10.0f                /* state scale: K2 * phys (tanh arg = 10x) */
#define LN2x2 1.3862943611f        /* 2*ln2: sigma(20*phys) = hs_neg(-LN2x2*K2arg) */
#define KHO   28.853901f           /* 20*log2(e), output sigma (phys arg) */

/* 1/(1+exp2(z)) -- exp2-based sigma for OFF-chain uses */
__device__ __forceinline__ float hs_neg(float z) {
    float e = __builtin_amdgcn_exp2f(z);
    return __builtin_amdgcn_rcpf(1.0f + e);
}

/* Pade(5,4) tanh, clamped: t = clamp(x(945+105x^2+x^4)/(945+420x^2+15x^4)).
   Exact +-1 in saturation (clamp); |err| <= ~1e-3 in transition band.
   ONE rcp on the serial chain (vs exp2+rcp). */
__device__ __forceinline__ float tanh_pade(float x) {
    float x2  = x * x;
    float den = fmaf(fmaf(15.0f, x2, 420.0f), x2, 945.0f);
    float pol = fmaf(x2, x2, fmaf(105.0f, x2, 945.0f));
    float num = x * pol;
    float r   = __builtin_amdgcn_rcpf(den);
    float t   = num * r;
    return fminf(fmaxf(t, -1.0f), 1.0f);
}

#define WAITV(N) asm volatile("s_waitcnt vmcnt(" #N ")" ::: "memory")
#define WAITL()  asm volatile("s_waitcnt lgkmcnt(0)" ::: "memory")
/* raw barrier (NOT __syncthreads: that drains vmcnt(0), killing DMA prefetch) */
#define TICK_BARRIER() do {                                   \
    asm volatile("s_waitcnt lgkmcnt(0)" ::: "memory");        \
    __builtin_amdgcn_s_barrier();                             \
    __builtin_amdgcn_sched_barrier(0); } while (0)

/* one 16-step input chunk = 12 f32x4 per lane (48 floats) */
#define DMA_CHUNK(SLOT, C) do {                                                \
    const float* g_ = row + (size_t)(C) * 48;                                  \
    _Pragma("unroll")                                                          \
    for (int j_ = 0; j_ < 12; ++j_) {                                          \
        __builtin_amdgcn_global_load_lds(                                      \
            (const __attribute__((address_space(1))) void*)(g_ + 4 * j_),      \
            (__attribute__((address_space(3))) void*)&s_in[SLOT][j_][0],       \
            16, 0, 0);                                                         \
    } } while (0)

__global__ __launch_bounds__(256, 1)
void xaj_pade2_kernel(const float* __restrict__ inp,
                      const float* __restrict__ p_wum,
                      const float* __restrict__ p_wlm,
                      const float* __restrict__ p_wdm,
                      const float* __restrict__ p_c,
                      const float* __restrict__ p_b,
                      const float* __restrict__ p_k1,
                      const float* __restrict__ p_k2,
                      const float* __restrict__ p_k3,
                      float* __restrict__ out)
{
    /* Lockstep tick T: W0->group T, W1->T-1, W2->T-2, W3->T-3 (barrier/tick).
       Handoffs K2-scaled. Chained sigmoids via tanh_pade (corrected signs:
       a = (1-tc)/2 so  X' = const + hh*tc, NOT - hh*tc).
       Rings: krem/kd1 ring-2; ku/kd2 ring-2; kwd ring-2; wup ring-4. */
    __shared__ f32x4        s_in  [3][12][64];   /* 36 KB input chunk ring */
    __shared__ float        s_krem[2][GROUP][64];
    __shared__ float        s_kd1 [2][GROUP][64];
    __shared__ float        s_ku  [2][GROUP][64];
    __shared__ float        s_kd2 [2][GROUP][64];
    __shared__ float        s_kwd [2][GROUP][64];
    __shared__ unsigned int s_wup [4][GROUP][64];

    const int lane  = threadIdx.x & 63;
    const int wv    = threadIdx.x >> 6;
    const int chain = blockIdx.x * 64 + lane;
    const float* __restrict__ row = inp + (size_t)chain * (3 * T_LEN);
    float* __restrict__ orow      = out + (size_t)chain * T_LEN;

    const float wum = p_wum[0], wlm = p_wlm[0], wdm = p_wdm[0];
    const float cc  = p_c[0],   bb  = p_b[0];
    const float k1  = p_k1[0],  k2  = p_k2[0],  k3 = p_k3[0];

    /* runoff_production called as (wu, wd, wl, p, wum, wdm, wlm, b, c) */
    const float w_total = (wum * 19.9f + 0.1f)
                        + (wdm * 30.0f + 60.0f)
                        + (wlm * 60.0f + 60.0f);
    const float inv_wt = 1.0f / w_total;
    const float c_s = cc * 0.19f + 0.01f;
    const float b_s = bb * 0.3f  + 0.1f;
    const float k1s = k1 * 0.69f + 0.01f;
    const float k2s = k2 * 0.69f + 0.01f;
    const float k3s = k3 * 0.89f + 0.01f;
    const float Kq = k1s + 0.5f * k2s * (1.0f - k1s)
                   + 0.25f * k3s * (1.0f - k1s) * (1.0f - k2s);
    const float C1 = inv_wt / K2;              /* un-K2-scale wu,wd */

    float Kst = 0.0f;                          /* K2-scaled scan state per wave */
    int s0 = 0, s1 = 1, s2 = 2;                /* input ring slots */

    if (wv == 0) { DMA_CHUNK(0, 0); DMA_CHUNK(1, 1); }

#pragma clang loop unroll(disable)
    for (int T = 0; T < NT; ++T) {
        if (wv == 0) {
            /* ---- W0: wu-chain. a=(1-tc)/2: Kwu' = (Kp-harg) + harg*tc ---- */
            if (T < NG) {
                const int g = T;
                WAITV(0);                      /* chunks 2g,2g+1 issued last tick */
                f32x4 fv[24];
#pragma unroll
                for (int j = 0; j < 12; ++j) fv[j]      = s_in[s0][j][lane];
#pragma unroll
                for (int j = 0; j < 12; ++j) fv[12 + j] = s_in[s1][j][lane];
                WAITL();                       /* reads done before slot reuse */
                __builtin_amdgcn_sched_barrier(0);
                const int c2 = 2 * g + 2, c3 = 2 * g + 3;
                if (c2 < 2 * NG) DMA_CHUNK(s2, c2);
                if (c3 < 2 * NG) DMA_CHUNK(s0, c3);
                float Kwu = Kst;
#pragma unroll
                for (int j = 0; j < GROUP; ++j) {
                    const int k0 = 3 * j, k2i = 3 * j + 2;
                    float pet = fv[k0 >> 2][k0 & 3];
                    float p   = fv[k2i >> 2][k2i & 3];
                    float K2pet = K2 * pet, Kp = K2 * p;
                    float arg  = K2pet - Kwu;            /* chain head */
                    float harg = 0.5f * arg;
                    float cst  = Kp - harg;
                    float tc   = tanh_pade(arg);         /* chained sigmoid */
                    float Kwun = fmaf(harg, tc, cst);    /* Kp - a*arg */
                    float Ky   = fmaf(harg, tc, harg);   /* (1-a)*arg  */
                    float Kd1  = Kwun - Kwu;
                    float hx   = hs_neg(-LN2x2 * Ky);    /* h(y), off-chain */
                    float Krem = hx * Ky;
                    s_krem[g & 1][j][lane] = Krem;
                    s_kd1 [g & 1][j][lane] = Kd1;
                    f16x2 pk = __builtin_amdgcn_cvt_pkrtz(Kwun, Kp);
                    s_wup[g & 3][j][lane] = __builtin_bit_cast(unsigned int, pk);
                    Kwu = Kwun;
                }
                Kst = Kwu;
                int t0 = s0; s0 = s2; s2 = s1; s1 = t0;  /* rotate ring */
            }
        } else if (wv == 1) {
            /* ---- W1: wl-chain. b2=(1-tc)/2: Kwl' = (A-hh) + hh*tc ---- */
            if (T >= 1 && T <= NG) {
                const int g = T - 1;
                float Kwl = Kst;
#pragma unroll
                for (int j = 0; j < GROUP; ++j) {
                    float Krem = s_krem[g & 1][j][lane];
                    float Kd1  = s_kd1 [g & 1][j][lane];
                    float hrem = hs_neg(-LN2x2 * Krem);  /* h(rem), off-chain */
                    float S    = Kwl + Kd1;
                    float A    = fmaf(-hrem, Krem, S);
                    float arg  = Kwl - Krem;             /* chain head */
                    float hh   = (0.5f * hrem) * arg;
                    float A2   = A - hh;
                    float tc   = tanh_pade(arg);         /* chained sigmoid */
                    float Kwln = fmaf(hh, tc, A2);       /* A - hrem*arg*b2 */
                    float Ket2 = S - Kwln;
                    s_ku [g & 1][j][lane] = Krem - Ket2;
                    s_kd2[g & 1][j][lane] = Kd1 - Ket2;
                    Kwl = Kwln;
                }
                Kst = Kwl;
            }
        } else if (wv == 2) {
            /* ---- W2: wd-chain. c2=(1-tc)/2: Kwd' = (A-hh) + hh*tc ---- */
            if (T >= 2 && T <= NG + 1) {
                const int g = T - 2;
                float Kwd = Kst;
#pragma unroll
                for (int j = 0; j < GROUP; ++j) {
                    float Ku  = s_ku [g & 1][j][lane];
                    float Kd2 = s_kd2[g & 1][j][lane];
                    float hu  = hs_neg(-LN2x2 * Ku);     /* h(u), off-chain */
                    float S2  = Kwd + Kd2;
                    float A   = fmaf(-hu, Ku, S2);
                    float arg = Kwd - Ku;                /* chain head */
                    float hh  = (0.5f * hu) * arg;
                    float A2  = A - hh;
                    float tc  = tanh_pade(arg);          /* chained sigmoid */
                    float Kwdn = fmaf(hh, tc, A2);       /* A - hu*arg*c2 */
                    s_kwd[g & 1][j][lane] = Kwdn;
                    Kwd = Kwdn;
                }
                Kst = Kwd;
            }
        } else {
            /* ---- W3: stateless output ---- */
            if (T >= 3) {
                const int g = T - 3;
                float qv[GROUP];
#pragma unroll
                for (int j = 0; j < GROUP; ++j) {
                    unsigned int pw = s_wup[g & 3][j][lane];
                    f16x2 pk = __builtin_bit_cast(f16x2, pw);
                    float Kwu_ = (float)pk[0];
                    float p    = (float)pk[1] * (1.0f / K2);
                    float Kwd_ = s_kwd[g & 1][j][lane];
                    float ru = Kwu_ * C1;
                    float rd = Kwd_ * C1;
                    float s2v = fmaf(c_s * ru, ru, (b_s * rd) * rd);
                    float ps = p - s2v;
                    float so = hs_neg(-KHO * ps);        /* h(ps) */
                    qv[j] = ps * so * Kq;
                }
                f32x4* o4 = (f32x4*)(orow + (size_t)g * GROUP);
#pragma unroll
                for (int i = 0; i < GROUP / 4; ++i) {
                    f32x4 q = {qv[4*i], qv[4*i+1], qv[4*i+2], qv[4*i+3]};
                    o4[i] = q;
                }
            }
        }
        TICK_BARRIER();
    }
}

extern "C" void kernel_launch(void* const* d_in, const int* in_sizes, int n_in,
                              void* d_out, int out_size, void* d_ws, size_t ws_size,
                              hipStream_t stream) {
    const float* inp = (const float*)d_in[0];
    const int B = out_size / T_LEN;            // 4096
    dim3 block(256), grid(B / 64);
    xaj_pade2_kernel<<<grid, block, 0, stream>>>(
        inp,
        (const float*)d_in[1],  // wum
        (const float*)d_in[2],  // wlm
        (const float*)d_in[3],  // wdm
        (const float*)d_in[4],  // c
        (const float*)d_in[5],  // b
        (const float*)d_in[6],  // k1
        (const float*)d_in[7],  // k2
        (const float*)d_in[8],  // k3
        (float*)d_out);
}

// Round 17
// 134.521 us; speedup vs baseline: 1.7333x; 1.1964x over previous
//
#include <hip/hip_runtime.h>

typedef float  f32x4 __attribute__((ext_vector_type(4)));
typedef __fp16 f16x2 __attribute__((ext_vector_type(2)));

#define T_LEN 2048
#define GROUP 32
#define NG    (T_LEN / GROUP)      /* 64 groups */
#define NT    (NG + 3)             /* 67 ticks, 4-stage lockstep pipeline */
#define KH    28.853901f           /* 20*log2(e) */

/* 1/(1+exp2(z)) */
__device__ __forceinline__ float hs_neg(float z) {
    float e = __builtin_amdgcn_exp2f(z);
    return __builtin_amdgcn_rcpf(1.0f + e);
}

#define WAITV(N) asm volatile("s_waitcnt vmcnt(" #N ")" ::: "memory")
#define WAITL()  asm volatile("s_waitcnt lgkmcnt(0)" ::: "memory")
/* raw barrier (NOT __syncthreads: that drains vmcnt(0), killing DMA prefetch) */
#define TICK_BARRIER() do {                                   \
    asm volatile("s_waitcnt lgkmcnt(0)" ::: "memory");        \
    __builtin_amdgcn_s_barrier();                             \
    __builtin_amdgcn_sched_barrier(0); } while (0)

/* one 16-step input chunk = 12 f32x4 per lane (48 floats) */
#define DMA_CHUNK(SLOT, C) do {                                                \
    const float* g_ = row + (size_t)(C) * 48;                                  \
    _Pragma("unroll")                                                          \
    for (int j_ = 0; j_ < 12; ++j_) {                                          \
        __builtin_amdgcn_global_load_lds(                                      \
            (const __attribute__((address_space(1))) void*)(g_ + 4 * j_),      \
            (__attribute__((address_space(3))) void*)&s_in[SLOT][j_][0],       \
            16, 0, 0);                                                         \
    } } while (0)

__global__ __launch_bounds__(256, 1)
void xaj_k32_kernel(const float* __restrict__ inp,
                    const float* __restrict__ p_wum,
                    const float* __restrict__ p_wlm,
                    const float* __restrict__ p_wdm,
                    const float* __restrict__ p_c,
                    const float* __restrict__ p_b,
                    const float* __restrict__ p_k1,
                    const float* __restrict__ p_k2,
                    const float* __restrict__ p_k3,
                    float* __restrict__ out)
{
    /* Lockstep tick T: W0->group T, W1->T-1, W2->T-2, W3->T-3 (barrier/tick).
       All handoffs K-scaled (KH*x).
       Rings: W0->W1 (krem,kd1) ring-2; W1->W2 (ku,kd2) ring-2; W2->W3 (kwd)
       ring-2; W0->W3 (wup: f16 Kwu | f16 p) ring-4 -- all barrier-separated. */
    __shared__ f32x4        s_in  [3][12][64];   /* 36 KB input chunk ring */
    __shared__ float        s_krem[2][GROUP][64];
    __shared__ float        s_kd1 [2][GROUP][64];
    __shared__ float        s_ku  [2][GROUP][64];
    __shared__ float        s_kd2 [2][GROUP][64];
    __shared__ float        s_kwd [2][GROUP][64];
    __shared__ unsigned int s_wup [4][GROUP][64];

    const int lane  = threadIdx.x & 63;
    const int wv    = threadIdx.x >> 6;
    const int chain = blockIdx.x * 64 + lane;
    const float* __restrict__ row = inp + (size_t)chain * (3 * T_LEN);
    float* __restrict__ orow      = out + (size_t)chain * T_LEN;

    const float wum = p_wum[0], wlm = p_wlm[0], wdm = p_wdm[0];
    const float cc  = p_c[0],   bb  = p_b[0];
    const float k1  = p_k1[0],  k2  = p_k2[0],  k3 = p_k3[0];

    /* runoff_production called as (wu, wd, wl, p, wum, wdm, wlm, b, c) */
    const float w_total = (wum * 19.9f + 0.1f)
                        + (wdm * 30.0f + 60.0f)
                        + (wlm * 60.0f + 60.0f);
    const float inv_wt = 1.0f / w_total;
    const float c_s = cc * 0.19f + 0.01f;
    const float b_s = bb * 0.3f  + 0.1f;
    const float k1s = k1 * 0.69f + 0.01f;
    const float k2s = k2 * 0.69f + 0.01f;
    const float k3s = k3 * 0.89f + 0.01f;
    const float Kq = k1s + 0.5f * k2s * (1.0f - k1s)
                   + 0.25f * k3s * (1.0f - k1s) * (1.0f - k2s);
    const float C1 = inv_wt / KH;              /* un-K-scale inside ratio */

    float Kst = 0.0f;                          /* K-scaled scan state per wave */
    int s0 = 0, s1 = 1, s2 = 2;                /* input ring slots */

    if (wv == 0) { DMA_CHUNK(0, 0); DMA_CHUNK(1, 1); }

#pragma clang loop unroll(disable)
    for (int T = 0; T < NT; ++T) {
        if (wv == 0) {
            /* ---- W0: wu-chain. Kwu' = Kp - arg*a, arg = KHpet - Kwu ---- */
            if (T < NG) {
                const int g = T;
                WAITV(0);                      /* chunks 2g,2g+1 (issued last
                                                  tick, ~2800cy old): no-wait */
                f32x4 fv[24];
#pragma unroll
                for (int j = 0; j < 12; ++j) fv[j]      = s_in[s0][j][lane];
#pragma unroll
                for (int j = 0; j < 12; ++j) fv[12 + j] = s_in[s1][j][lane];
                WAITL();                       /* reads done before slot reuse */
                __builtin_amdgcn_sched_barrier(0);
                const int c2 = 2 * g + 2, c3 = 2 * g + 3;
                if (c2 < 2 * NG) DMA_CHUNK(s2, c2);
                if (c3 < 2 * NG) DMA_CHUNK(s0, c3);
                float Kwu = Kst;
#pragma unroll
                for (int j = 0; j < GROUP; ++j) {
                    const int k0 = 3 * j, k2i = 3 * j + 2;
                    float pet = fv[k0 >> 2][k0 & 3];
                    float p   = fv[k2i >> 2][k2i & 3];
                    float KHpet = KH * pet, Kp = KH * p;
                    float arg  = KHpet - Kwu;            /* chain head */
                    float a    = hs_neg(arg);            /* h(wu-pet) */
                    float Kwun = fmaf(-arg, a, Kp);      /* chain tail */
                    float Kd1  = Kwun - Kwu;
                    float Ky   = arg + (Kwun - Kp);      /* = arg*(1-a) */
                    float hx   = hs_neg(-Ky);            /* h(pet-et1), ILP */
                    float Krem = hx * Ky;
                    s_krem[g & 1][j][lane] = Krem;
                    s_kd1 [g & 1][j][lane] = Kd1;
                    f16x2 pk = __builtin_amdgcn_cvt_pkrtz(Kwun, p);
                    s_wup[g & 3][j][lane] = __builtin_bit_cast(unsigned int, pk);
                    Kwu = Kwun;
                }
                Kst = Kwu;
                int t0 = s0; s0 = s2; s2 = s1; s1 = t0;  /* rotate ring */
            }
        } else if (wv == 1) {
            /* ---- W1: wl-chain. Kwl' = A - b2*harg ---- */
            if (T >= 1 && T <= NG) {
                const int g = T - 1;
                float Kwl = Kst;
#pragma unroll
                for (int j = 0; j < GROUP; ++j) {
                    float Krem = s_krem[g & 1][j][lane];
                    float Kd1  = s_kd1 [g & 1][j][lane];
                    float hrem = hs_neg(-Krem);          /* h(rem), ILP */
                    float S    = Kwl + Kd1;
                    float A    = fmaf(-hrem, Krem, S);
                    float arg  = Kwl - Krem;             /* chain head */
                    float b2   = hs_neg(arg);            /* h(rem-wl) */
                    float harg = hrem * arg;
                    float Kwln = fmaf(-b2, harg, A);     /* chain tail */
                    float Ket2 = S - Kwln;
                    s_ku [g & 1][j][lane] = Krem - Ket2;
                    s_kd2[g & 1][j][lane] = Kd1 - Ket2;
                    Kwl = Kwln;
                }
                Kst = Kwl;
            }
        } else if (wv == 2) {
            /* ---- W2: wd-chain. Kwd' = A2 - c2*harg ---- */
            if (T >= 2 && T <= NG + 1) {
                const int g = T - 2;
                float Kwd = Kst;
#pragma unroll
                for (int j = 0; j < GROUP; ++j) {
                    float Ku  = s_ku [g & 1][j][lane];
                    float Kd2 = s_kd2[g & 1][j][lane];
                    float hu  = hs_neg(-Ku);             /* h(u), ILP */
                    float S2  = Kwd + Kd2;
                    float A2  = fmaf(-hu, Ku, S2);
                    float arg = Kwd - Ku;                /* chain head */
                    float c2v = hs_neg(arg);             /* h(u-wd) */
                    float harg = hu * arg;
                    float Kwdn = fmaf(-c2v, harg, A2);   /* chain tail */
                    s_kwd[g & 1][j][lane] = Kwdn;
                    Kwd = Kwdn;
                }
                Kst = Kwd;
            }
        } else {
            /* ---- W3: stateless output ---- */
            if (T >= 3) {
                const int g = T - 3;
                float qv[GROUP];
#pragma unroll
                for (int j = 0; j < GROUP; ++j) {
                    unsigned int pw = s_wup[g & 3][j][lane];
                    f16x2 pk = __builtin_bit_cast(f16x2, pw);
                    float Kwu_ = (float)pk[0];
                    float p    = (float)pk[1];
                    float Kwd_ = s_kwd[g & 1][j][lane];
                    float ru = Kwu_ * C1;
                    float rd = Kwd_ * C1;
                    float s2v = fmaf(c_s * ru, ru, (b_s * rd) * rd);
                    float ps = p - s2v;
                    float so = hs_neg(-KH * ps);         /* h(ps) */
                    qv[j] = ps * so * Kq;
                }
                f32x4* o4 = (f32x4*)(orow + (size_t)g * GROUP);
#pragma unroll
                for (int i = 0; i < GROUP / 4; ++i) {
                    f32x4 q = {qv[4*i], qv[4*i+1], qv[4*i+2], qv[4*i+3]};
                    o4[i] = q;
                }
            }
        }
        TICK_BARRIER();
    }
}

extern "C" void kernel_launch(void* const* d_in, const int* in_sizes, int n_in,
                              void* d_out, int out_size, void* d_ws, size_t ws_size,
                              hipStream_t stream) {
    const float* inp = (const float*)d_in[0];
    const int B = out_size / T_LEN;            // 4096
    dim3 block(256), grid(B / 64);
    xaj_k32_kernel<<<grid, block, 0, stream>>>(
        inp,
        (const float*)d_in[1],  // wum
        (const float*)d_in[2],  // wlm
        (const float*)d_in[3],  // wdm
        (const float*)d_in[4],  // c
        (const float*)d_in[5],  // b
        (const float*)d_in[6],  // k1
        (const float*)d_in[7],  // k2
        (const float*)d_in[8],  // k3
        (float*)d_out);
}